// Round 10
// baseline (258.644 us; speedup 1.0000x reference)
//
#include <hip/hip_runtime.h>

// TemporalLSTM round 10 (gfx950): R9 + xn prefetch restored + merged c-update rcp.
//
// R9 post-mortem: busy/SIMD-step 1790->1340 (-450; trans cut predicted -448).
// Remaining 2196 cyc/step = 1340 busy (trans ~830 dominant) + 856 idle (serial
// step entry: R9's 4-serial-mfma chain + no prefetch to fill pointwise window).
// R10: (1) xn[8] prefetch (R5-proven spill-free): x-proj mfmas of step t+1
// issue during step t's pointwise; h-chain back to 3 mfmas, acc init free.
// (2) merged c-denominator: c'_new = [c'*E + 2L(1-v)*F]/(E*F), E=(1+u)(1+v),
// F=1+w -> 12 trans/pair (48/step). (3) shared zero C quad for xn mfmas.
//
// Structure (verified R5/R9): A = weights (resident VGPR frags), B = h.
// Gate-row permutation  tile t8 = hb*4+g :  row m -> R = 32g + 8*(m>>2) + 4*hb + (m&3)
// gives C/D (m=4q+r, n): acc[hb*4+g][r] = gate g, batch col n, j = 8q+4hb+r,
// and the next-step B-frag (B[k][n], k=8q+kk -> h[n][8q+kk]) is the lane's own
// pointwise output. No LDS round-trip, no step barriers. 1024 single-wave blocks.
// Weights pre-scaled by log2e (2*log2e for g-gate); c kept in 2L units so every
// exp2 arg is a raw acc value with a free neg modifier.

typedef __bf16 bf16x8 __attribute__((ext_vector_type(8)));
typedef float  f32x4  __attribute__((ext_vector_type(4)));
typedef unsigned int u32;

constexpr int kT = 200, kIN = 5, kH = 32;
constexpr int CT = 40;   // timesteps of x staged per phase (200 = 5*40)

constexpr float kL  = 1.4426950408889634f;   // log2(e)
constexpr float k2L = 2.8853900817779268f;   // 2*log2(e)

union FragU { bf16x8 v; __bf16 b[8]; unsigned short s[8]; u32 u[4]; uint4 q4; };

__device__ __forceinline__ unsigned short bfbits(__bf16 b) {
    union { __bf16 b; unsigned short s; } u; u.b = b; return u.s;
}
__device__ __forceinline__ void split2(float x, __bf16& hi, __bf16& lo) {
    hi = (__bf16)x;                 // RNE cvt
    lo = (__bf16)(x - (float)hi);   // residual, |lo| <= 2^-9 |x|
}

__global__ __launch_bounds__(64) void lstm_reg6(
    const float* __restrict__ x,     // [B,200,5]
    const float* __restrict__ W_ih,  // [128,5]
    const float* __restrict__ W_hh,  // [128,32]
    const float* __restrict__ b_ih,  // [128]
    const float* __restrict__ b_hh,  // [128]
    const float* __restrict__ W_fc,  // [2,32]
    const float* __restrict__ b_fc,  // [2]
    float* __restrict__ out)         // [B,2]
{
    __shared__ uint4 xbuf[CT][34];   // cols 0..31: x B-frags; 32/33: const quads

    const int lane = threadIdx.x;    // single-wave block
    const int n16  = lane & 15;
    const int q    = lane >> 4;
    const int b0   = blockIdx.x * 16;

    // ---- weight A-frags resident in VGPRs (A[m][k]: m = lane&15, k = q*8+j) ----
    // scaled by kL (gates i,f,o) or k2L (gate g) before the hi/lo split.
    bf16x8 whhA_h[8], whhA_l[8], wihA[8];
#pragma unroll
    for (int t8 = 0; t8 < 8; ++t8) {
        const int g  = t8 & 3, hb = t8 >> 2;
        const int R  = g * 32 + 8 * (n16 >> 2) + 4 * hb + (n16 & 3);  // gate row
        const float sc = (g == 2) ? k2L : kL;
        FragU H, L;
#pragma unroll
        for (int j = 0; j < 8; ++j)
            split2(sc * W_hh[R * kH + q * 8 + j], H.b[j], L.b[j]);
        whhA_h[t8] = H.v; whhA_l[t8] = L.v;

        float wr[5];
#pragma unroll
        for (int i = 0; i < 5; ++i) wr[i] = sc * W_ih[R * kIN + i];
        __bf16 bh, bl;
        split2(sc * (b_ih[R] + b_hh[R]), bh, bl);

        FragU F;
        F.u[0] = F.u[1] = F.u[2] = F.u[3] = 0u;
        if (q == 0) {                       // k0..7
#pragma unroll
            for (int i = 0; i < 5; ++i) F.b[i] = (__bf16)wr[i];       // k0..4: Wih_hi
#pragma unroll
            for (int i = 0; i < 3; ++i) F.b[5 + i] = (__bf16)wr[i];   // k5..7: Wih_hi(0..2)
        } else if (q == 1) {                // k8..15
            F.b[0] = (__bf16)wr[3];                                   // k8:  Wih_hi(3)
            F.b[1] = (__bf16)wr[4];                                   // k9:  Wih_hi(4)
#pragma unroll
            for (int i = 0; i < 5; ++i) {                             // k10..14: Wih_lo
                __bf16 hbb, lbb; split2(wr[i], hbb, lbb);
                F.b[2 + i] = lbb;
            }
            F.b[7] = bh;                                              // k15: bias_hi
        } else if (q == 2) {
            F.b[0] = bl;                                              // k16: bias_lo
        }
        wihA[t8] = F.v;
    }

    // ---- const x-frag quads (written once) ----
    for (int t2 = lane; t2 < CT; t2 += 64) {
        xbuf[t2][32] = make_uint4(0x3F80u, 0u, 0u, 0u);   // quad2: k16 B=1.0 (bf16)
        xbuf[t2][33] = make_uint4(0u, 0u, 0u, 0u);        // quad3: zeros
    }

    const int col = (q < 2) ? (n16 * 2 + q) : (30 + q);   // loop-invariant frag column
    const f32x4 zf4 = {0.f, 0.f, 0.f, 0.f};               // shared C for all xn mfmas

    // recurrence state, fully in registers. c8 is in 2L units (c_scaled = 2L*c).
    float c8[8] = {0.f, 0.f, 0.f, 0.f, 0.f, 0.f, 0.f, 0.f};
    FragU Bh, Bl;                          // h as bf16 hi/lo B-frags
    Bh.u[0] = Bh.u[1] = Bh.u[2] = Bh.u[3] = 0u;
    Bl.u[0] = Bl.u[1] = Bl.u[2] = Bl.u[3] = 0u;

    f32x4 xn[8];                           // pipelined x-proj + bias (R5-proven)

    for (int phase = 0; phase < kT / CT; ++phase) {
        // ---- stage CT steps of x as ready-made B-frags (64 lanes, 16 batches) ----
        {
            const int mm = lane >> 2, pp = lane & 3;       // batch row, 10-step chunk
            const float2* xr2 = (const float2*)(x + (size_t)(b0 + mm) * (kT * kIN)
                                                  + (size_t)(phase * CT + pp * 10) * kIN);
            float xv[50];
#pragma unroll
            for (int i = 0; i < 25; ++i) {
                float2 v = xr2[i];
                xv[2 * i] = v.x; xv[2 * i + 1] = v.y;
            }
#pragma unroll
            for (int s5 = 0; s5 < 10; ++s5) {
                u32 xh[5], xl[5];
#pragma unroll
                for (int i = 0; i < 5; ++i) {
                    __bf16 hbb, lbb; split2(xv[s5 * 5 + i], hbb, lbb);
                    xh[i] = bfbits(hbb); xl[i] = bfbits(lbb);
                }
                uint4 f0 = make_uint4(xh[0] | (xh[1] << 16),
                                      xh[2] | (xh[3] << 16),
                                      xh[4] | (xl[0] << 16),
                                      xl[1] | (xl[2] << 16));
                uint4 f1 = make_uint4(xl[3] | (xl[4] << 16),
                                      xh[0] | (xh[1] << 16),
                                      xh[2] | (xh[3] << 16),
                                      xh[4] | (0x3F80u << 16));   // k15: B = 1.0
                const int tc = pp * 10 + s5;
                xbuf[tc][mm * 2 + 0] = f0;
                xbuf[tc][mm * 2 + 1] = f1;
            }
        }
        __syncthreads();

        // xn for the first step of this phase
        {
            FragU xg; xg.q4 = xbuf[0][col];
#pragma unroll
            for (int t8 = 0; t8 < 8; ++t8)
                xn[t8] = __builtin_amdgcn_mfma_f32_16x16x32_bf16(wihA[t8], xg.v, zf4, 0, 0, 0);
        }

#pragma unroll 1
        for (int tc = 0; tc < CT; ++tc) {
            // h-dependent GEMM: 3-mfma split-bf16 chain, acc init = prefetched xn
            f32x4 acc[8];
#pragma unroll
            for (int t8 = 0; t8 < 8; ++t8) {
                f32x4 a = __builtin_amdgcn_mfma_f32_16x16x32_bf16(whhA_h[t8], Bh.v, xn[t8], 0, 0, 0);
                a = __builtin_amdgcn_mfma_f32_16x16x32_bf16(whhA_h[t8], Bl.v, a, 0, 0, 0);
                a = __builtin_amdgcn_mfma_f32_16x16x32_bf16(whhA_l[t8], Bh.v, a, 0, 0, 0);
                acc[t8] = a;
            }

            // prefetch next step's x-proj (h-independent; fills the pointwise window)
            {
                const int tn = (tc + 1 < CT) ? tc + 1 : 0;
                FragU xg; xg.q4 = xbuf[tn][col];
#pragma unroll
                for (int t8 = 0; t8 < 8; ++t8)
                    xn[t8] = __builtin_amdgcn_mfma_f32_16x16x32_bf16(wihA[t8], xg.v, zf4, 0, 0, 0);
            }

            // pointwise, cells in pairs. acc pre-scaled: i,f,o = L*a; g = 2L*a;
            // c8 in 2L units. Merged c-update:
            //   c' = [c'*E + 2L(1-v)*F] / (E*F),  E=(1+u)(1+v), F=1+w
            // with one paired rcp for (E*F) across the two cells.
#pragma unroll
            for (int m2 = 0; m2 < 4; ++m2) {
                const int j0 = 2 * m2, j1 = j0 + 1;
                const int hb = j0 >> 2;                   // same for both cells
                const int r0 = j0 & 3, r1 = j1 & 3;
                float ai0 = acc[hb * 4 + 0][r0], af0 = acc[hb * 4 + 1][r0];
                float ag0 = acc[hb * 4 + 2][r0], ao0 = acc[hb * 4 + 3][r0];
                float ai1 = acc[hb * 4 + 0][r1], af1 = acc[hb * 4 + 1][r1];
                float ag1 = acc[hb * 4 + 2][r1], ao1 = acc[hb * 4 + 3][r1];

                float u0 = __builtin_amdgcn_exp2f(-ai0), v0 = __builtin_amdgcn_exp2f(-ag0);
                float w0 = __builtin_amdgcn_exp2f(-af0), p0 = __builtin_amdgcn_exp2f(-ao0);
                float u1 = __builtin_amdgcn_exp2f(-ai1), v1 = __builtin_amdgcn_exp2f(-ag1);
                float w1 = __builtin_amdgcn_exp2f(-af1), p1 = __builtin_amdgcn_exp2f(-ao1);

                float E0 = (1.0f + u0) * (1.0f + v0);
                float E1 = (1.0f + u1) * (1.0f + v1);
                float F0 = 1.0f + w0, F1 = 1.0f + w1;
                float D0 = E0 * F0, D1 = E1 * F1;
                float rD = __builtin_amdgcn_rcpf(D0 * D1);

                float t0 = fmaf(v0, -k2L, k2L);           // 2L*(1-v0)
                float t1 = fmaf(v1, -k2L, k2L);
                float N0 = fmaf(c8[j0], E0, t0 * F0);
                float N1 = fmaf(c8[j1], E1, t1 * F1);
                float c0 = N0 * (D1 * rD);
                float c1 = N1 * (D0 * rD);
                c0 = fmaxf(c0, -35.0f);                   // tanh==-1 to 2e-11 here;
                c1 = fmaxf(c1, -35.0f);                   // bounds s for paired rcp
                c8[j0] = c0; c8[j1] = c1;

                float s0 = __builtin_amdgcn_exp2f(-c0);
                float s1 = __builtin_amdgcn_exp2f(-c1);
                float G0 = (1.0f + p0) * (1.0f + s0);     // o*tanh(c) denominator
                float G1 = (1.0f + p1) * (1.0f + s1);
                float rG = __builtin_amdgcn_rcpf(G0 * G1);
                float h0 = (1.0f - s0) * (G1 * rG);       // h = o*tanh(c)
                float h1 = (1.0f - s1) * (G0 * rG);

                split2(h0, Bh.b[j0], Bl.b[j0]);
                split2(h1, Bh.b[j1], Bl.b[j1]);
            }
        }
    }

    // ---- epilogue: reconstruct h (hi+lo, ~2^-17) and apply the FC head ----
    __syncthreads();
    float* hfin = (float*)xbuf;            // reuse LDS: [16][33] f32
#pragma unroll
    for (int jj = 0; jj < 8; ++jj)
        hfin[n16 * 33 + q * 8 + jj] = (float)Bh.b[jj] + (float)Bl.b[jj];
    __syncthreads();
    if (lane < 32) {
        const int m = lane >> 1, o = lane & 1;
        float s = b_fc[o];
#pragma unroll
        for (int j = 0; j < kH; ++j)
            s = fmaf(hfin[m * 33 + j], W_fc[o * kH + j], s);
        out[(size_t)(b0 + m) * 2 + o] = s;
    }
}

extern "C" void kernel_launch(void* const* d_in, const int* in_sizes, int n_in,
                              void* d_out, int out_size, void* d_ws, size_t ws_size,
                              hipStream_t stream) {
    const float* x    = (const float*)d_in[0];
    const float* W_ih = (const float*)d_in[1];
    const float* W_hh = (const float*)d_in[2];
    const float* b_ih = (const float*)d_in[3];
    const float* b_hh = (const float*)d_in[4];
    const float* W_fc = (const float*)d_in[5];
    const float* b_fc = (const float*)d_in[6];
    float* out = (float*)d_out;

    // 16384 batches / 16 per wave = 1024 single-wave blocks
    hipLaunchKernelGGL(lstm_reg6, dim3(1024), dim3(64), 0, stream,
                       x, W_ih, W_hh, b_ih, b_hh, W_fc, b_fc, out);
}